// Round 1
// baseline (670.101 us; speedup 1.0000x reference)
//
#include <hip/hip_runtime.h>

// ============================================================================
// t3 recurrence via affine-operator doubling + bf16x3 split MFMA GEMMs.
//
// Reference: t3=t1; repeat 50x { t3 = t1 + t2@t3; t3 = t1 + t3@t2 }; out=t3+t1
// Fused step: t3 <- C + t2 @ t3 @ t2,  C = t1 + t1@t2
// Operator F=(S,P): X -> S + P X P.  F^2k: S'=S+P S P, P'=P P (3 matmuls)
// Apply F^k(X): T=P@X; X'=S+T@P (2 matmuls).  50 = 2 + 16*3  ->  21 matmuls.
//
// Every matrix is kept as pre-split bf16 hi/lo pairs in the layout its
// consumers need: A-form = row-major [m][k], B-form = transposed [n][k].
// fp32 masters kept only where needed as GEMM C-inputs (S) / output (X=d_out).
// ============================================================================

typedef __bf16 bf16;
typedef bf16 bf16x8 __attribute__((ext_vector_type(8)));
typedef float f32x4 __attribute__((ext_vector_type(4)));
typedef float f32x16 __attribute__((ext_vector_type(16)));

#define LD 1024
#define BM 128
#define BN 64
#define BK 32
#define NKS (LD / BK)   // 32 K-steps
#define SK 40           // LDS k-stride (bf16): 80B rows, 16B aligned, ~2-way banks

__device__ __forceinline__ f32x16 mfma16(bf16x8 a, bf16x8 b, f32x16 c) {
  return __builtin_amdgcn_mfma_f32_32x32x16_bf16(a, b, c, 0, 0, 0);
}

// D = A@B (+C1) (+C2); outputs: Of (fp32), Orh/Orl (bf16 hi/lo row-major),
// Oth/Otl (bf16 hi/lo transposed [n][m]). Null pointer = skip that output.
// A* are row-major [m][k] bf16; B* are transposed [n][k] bf16.
__global__ __launch_bounds__(256) void gemm_k(
    const bf16* __restrict__ Ah, const bf16* __restrict__ Al,
    const bf16* __restrict__ Bh, const bf16* __restrict__ Bl,
    const float* __restrict__ C1, const float* __restrict__ C2,
    float* __restrict__ Of,
    bf16* __restrict__ Orh, bf16* __restrict__ Orl,
    bf16* __restrict__ Oth, bf16* __restrict__ Otl)
{
  __shared__ bf16 sA[2][2][BM * SK];   // [dbuf][hi/lo][...]
  __shared__ bf16 sB[2][2][BN * SK];

  const int tid  = threadIdx.x;
  const int lane = tid & 63;
  const int wave = tid >> 6;

  // XCD-aware bijective swizzle (128 wgs, 8 XCDs, 128%8==0)
  const int id  = blockIdx.y * 16 + blockIdx.x;
  const int sid = (id & 7) * 16 + (id >> 3);
  const int bm = (sid >> 4) * BM;   // 0..7  -> row tile
  const int bn = (sid & 15) * BN;   // 0..15 -> col tile

  // staging mapping: A-tile 128x32 (16 elem/thr), B-tile 64x32 (8 elem/thr)
  const int ar = tid >> 1;
  const int ac = (tid & 1) * 16;
  const int br = tid >> 2;
  const int bc = (tid & 3) * 8;

  const bf16* gAh = Ah + (size_t)(bm + ar) * LD + ac;
  const bf16* gAl = Al + (size_t)(bm + ar) * LD + ac;
  const bf16* gBh = Bh + (size_t)(bn + br) * LD + bc;
  const bf16* gBl = Bl + (size_t)(bn + br) * LD + bc;

  bf16x8 rah0, rah1, ral0, ral1, rbh, rbl;

  auto load_tile = [&](int kt) {
    const int o = kt * BK;
    rah0 = *(const bf16x8*)(gAh + o);
    rah1 = *(const bf16x8*)(gAh + o + 8);
    ral0 = *(const bf16x8*)(gAl + o);
    ral1 = *(const bf16x8*)(gAl + o + 8);
    rbh  = *(const bf16x8*)(gBh + o);
    rbl  = *(const bf16x8*)(gBl + o);
  };
  auto store_tile = [&](int buf) {
    *(bf16x8*)&sA[buf][0][ar * SK + ac]     = rah0;
    *(bf16x8*)&sA[buf][0][ar * SK + ac + 8] = rah1;
    *(bf16x8*)&sA[buf][1][ar * SK + ac]     = ral0;
    *(bf16x8*)&sA[buf][1][ar * SK + ac + 8] = ral1;
    *(bf16x8*)&sB[buf][0][br * SK + bc]     = rbh;
    *(bf16x8*)&sB[buf][1][br * SK + bc]     = rbl;
  };

  // wave -> 64x32 output: two 32x32 MFMA tiles stacked in m
  const int wm  = wave >> 1;
  const int wn  = wave & 1;
  const int l31 = lane & 31;
  const int lh  = lane >> 5;
  const int lh8 = lh * 8;

  const int aoff0 = (wm * 64 + l31) * SK + lh8;
  const int aoff1 = (wm * 64 + 32 + l31) * SK + lh8;
  const int boff  = (wn * 32 + l31) * SK + lh8;

  f32x16 acc0 = {0,0,0,0,0,0,0,0,0,0,0,0,0,0,0,0};
  f32x16 acc1 = {0,0,0,0,0,0,0,0,0,0,0,0,0,0,0,0};

  auto compute = [&](int buf) {
#pragma unroll
    for (int c = 0; c < 2; ++c) {          // two k=16 chunks
      const int co = c * 16;
      bf16x8 a0h = *(const bf16x8*)&sA[buf][0][aoff0 + co];
      bf16x8 a0l = *(const bf16x8*)&sA[buf][1][aoff0 + co];
      bf16x8 a1h = *(const bf16x8*)&sA[buf][0][aoff1 + co];
      bf16x8 a1l = *(const bf16x8*)&sA[buf][1][aoff1 + co];
      bf16x8 bh  = *(const bf16x8*)&sB[buf][0][boff + co];
      bf16x8 bl  = *(const bf16x8*)&sB[buf][1][boff + co];
      // bf16x3: hi*hi + hi*lo + lo*hi, two independent acc chains for ILP
      acc0 = mfma16(a0h, bh, acc0);
      acc1 = mfma16(a1h, bh, acc1);
      acc0 = mfma16(a0h, bl, acc0);
      acc1 = mfma16(a1h, bl, acc1);
      acc0 = mfma16(a0l, bh, acc0);
      acc1 = mfma16(a1l, bh, acc1);
    }
  };

  load_tile(0);
  store_tile(0);
  __syncthreads();
  int buf = 0;
  for (int kt = 0; kt < NKS; ++kt) {
    if (kt + 1 < NKS) load_tile(kt + 1);   // loads in flight during compute
    compute(buf);
    if (kt + 1 < NKS) store_tile(buf ^ 1); // implicit vmcnt wait here
    __syncthreads();
    buf ^= 1;
  }
  // (final __syncthreads above: LDS now reusable as epilogue scratch)

  const int gc = bn + wn * 32 + l31;
#pragma unroll
  for (int tf = 0; tf < 2; ++tf) {
    const int gr0 = bm + wm * 64 + tf * 32;
    float v[16];
#pragma unroll
    for (int r = 0; r < 16; ++r) v[r] = tf ? acc1[r] : acc0[r];

    // C/D layout (32x32x16): row = (r&3)+8*(r>>2)+4*lh, col = l31
    if (C1) {
#pragma unroll
      for (int r = 0; r < 16; ++r)
        v[r] += C1[(size_t)(gr0 + ((r & 3) + 8 * (r >> 2) + 4 * lh)) * LD + gc];
    }
    if (C2) {
#pragma unroll
      for (int r = 0; r < 16; ++r)
        v[r] += C2[(size_t)(gr0 + ((r & 3) + 8 * (r >> 2) + 4 * lh)) * LD + gc];
    }
    if (Of) {
#pragma unroll
      for (int r = 0; r < 16; ++r)
        Of[(size_t)(gr0 + ((r & 3) + 8 * (r >> 2) + 4 * lh)) * LD + gc] = v[r];
    }
    if (Orh) {
#pragma unroll
      for (int r = 0; r < 16; ++r) {
        float x = v[r];
        bf16 h  = (bf16)x;
        bf16 lo = (bf16)(x - (float)h);
        size_t idx = (size_t)(gr0 + ((r & 3) + 8 * (r >> 2) + 4 * lh)) * LD + gc;
        Orh[idx] = h;
        Orl[idx] = lo;
      }
    }
    if (Oth) {
      // per-wave private 32x33 f32 scratch inside sA (all waves past barrier)
      float* tl = ((float*)&sA[0][0][0]) + wave * (32 * 33);
#pragma unroll
      for (int r = 0; r < 16; ++r)
        tl[((r & 3) + 8 * (r >> 2) + 4 * lh) * 33 + l31] = v[r];
      float tv[16];
#pragma unroll
      for (int j = 0; j < 16; ++j)
        tv[j] = tl[(lh * 16 + j) * 33 + l31];      // lane owns col n=l31
      bf16x8 th0, th1, tb0, tb1;
#pragma unroll
      for (int j = 0; j < 16; ++j) {
        bf16 h  = (bf16)tv[j];
        bf16 lo = (bf16)(tv[j] - (float)h);
        if (j < 8) { th0[j] = h; tb0[j] = lo; }
        else       { th1[j - 8] = h; tb1[j - 8] = lo; }
      }
      bf16* ph = Oth + (size_t)gc * LD + gr0 + lh * 16;
      bf16* pl = Otl + (size_t)gc * LD + gr0 + lh * 16;
      *(bf16x8*)ph = th0; *(bf16x8*)(ph + 8) = th1;
      *(bf16x8*)pl = tb0; *(bf16x8*)(pl + 8) = tb1;
    }
  }
}

// One-time split/transpose of the fp32 inputs into A-form and B-form bf16.
__global__ __launch_bounds__(256) void prep_k(
    const float* __restrict__ t1, const float* __restrict__ t2,
    bf16* __restrict__ Ah1, bf16* __restrict__ Al1,
    bf16* __restrict__ Bh1, bf16* __restrict__ Bl1,
    bf16* __restrict__ Ah2, bf16* __restrict__ Al2,
    bf16* __restrict__ Bh2, bf16* __restrict__ Bl2)
{
  __shared__ float tl[64 * 65];
  const int z = blockIdx.z;
  const float* src = z ? t2 : t1;
  bf16* Ah = z ? Ah2 : Ah1;
  bf16* Al = z ? Al2 : Al1;
  bf16* Bh = z ? Bh2 : Bh1;
  bf16* Bl = z ? Bl2 : Bl1;

  const int tid = threadIdx.x;
  const int r0 = blockIdx.y * 64, c0 = blockIdx.x * 64;
  const int r  = tid >> 2;
  const int cc = (tid & 3) * 16;

  float vv[16];
#pragma unroll
  for (int q = 0; q < 4; ++q) {
    f32x4 x = *(const f32x4*)&src[(size_t)(r0 + r) * LD + c0 + cc + q * 4];
#pragma unroll
    for (int e = 0; e < 4; ++e) vv[q * 4 + e] = x[e];
  }
  bf16x8 h8[2], l8[2];
#pragma unroll
  for (int j = 0; j < 16; ++j) {
    bf16 h  = (bf16)vv[j];
    bf16 lo = (bf16)(vv[j] - (float)h);
    h8[j >> 3][j & 7] = h;
    l8[j >> 3][j & 7] = lo;
    tl[r * 65 + cc + j] = vv[j];
  }
  {
    bf16* p = Ah + (size_t)(r0 + r) * LD + c0 + cc;
    *(bf16x8*)p = h8[0]; *(bf16x8*)(p + 8) = h8[1];
    bf16* q = Al + (size_t)(r0 + r) * LD + c0 + cc;
    *(bf16x8*)q = l8[0]; *(bf16x8*)(q + 8) = l8[1];
  }
  __syncthreads();
  float tv[16];
#pragma unroll
  for (int j = 0; j < 16; ++j) tv[j] = tl[(cc + j) * 65 + r];
#pragma unroll
  for (int j = 0; j < 16; ++j) {
    bf16 h  = (bf16)tv[j];
    bf16 lo = (bf16)(tv[j] - (float)h);
    h8[j >> 3][j & 7] = h;
    l8[j >> 3][j & 7] = lo;
  }
  {
    bf16* p = Bh + (size_t)(c0 + r) * LD + r0 + cc;
    *(bf16x8*)p = h8[0]; *(bf16x8*)(p + 8) = h8[1];
    bf16* q = Bl + (size_t)(c0 + r) * LD + r0 + cc;
    *(bf16x8*)q = l8[0]; *(bf16x8*)(q + 8) = l8[1];
  }
}

extern "C" void kernel_launch(void* const* d_in, const int* in_sizes, int n_in,
                              void* d_out, int out_size, void* d_ws, size_t ws_size,
                              hipStream_t stream) {
  (void)in_sizes; (void)n_in; (void)out_size;
  const float* t1 = (const float*)d_in[0];
  const float* t2 = (const float*)d_in[1];
  float* X = (float*)d_out;

  const size_t F32B = (size_t)LD * LD * 4;   // 4 MB
  const size_t B16B = (size_t)LD * LD * 2;   // 2 MB
  if (ws_size < F32B + 22 * B16B) return;    // need 48 MB scratch

  char* p = (char*)d_ws;
  float* S = (float*)p; p += F32B;
  auto nb = [&]() { bf16* r = (bf16*)p; p += B16B; return r; };
  bf16 *SBh = nb(), *SBl = nb();
  bf16 *XBh = nb(), *XBl = nb();
  bf16 *TAh = nb(), *TAl = nb();
  bf16 *t1Ah = nb(), *t1Al = nb(), *t1Bh = nb(), *t1Bl = nb();
  bf16 *t2Ah = nb(), *t2Al = nb(), *t2Bh = nb(), *t2Bl = nb();
  bf16 *P0Ah = nb(), *P0Al = nb(), *P0Bh = nb(), *P0Bl = nb();
  bf16 *P1Ah = nb(), *P1Al = nb(), *P1Bh = nb(), *P1Bl = nb();

  dim3 gg(16, 8), bb(256);
  auto G = [&](const bf16* ah, const bf16* al, const bf16* bh, const bf16* bl,
               const float* c1, const float* c2, float* of,
               bf16* orh, bf16* orl, bf16* oth, bf16* otl) {
    gemm_k<<<gg, bb, 0, stream>>>(ah, al, bh, bl, c1, c2, of, orh, orl, oth, otl);
  };

  prep_k<<<dim3(16, 16, 2), 256, 0, stream>>>(t1, t2,
      t1Ah, t1Al, t1Bh, t1Bl, t2Ah, t2Al, t2Bh, t2Bl);

  // S = C = t1 + t1@t2          (fp32 + B-form)
  G(t1Ah, t1Al, t2Bh, t2Bl, t1, nullptr, S, nullptr, nullptr, SBh, SBl);
  // F^1 -> F^2  (P1 = t2)
  G(t2Ah, t2Al, SBh, SBl, nullptr, nullptr, nullptr, TAh, TAl, nullptr, nullptr); // T=P@S
  G(TAh, TAl, t2Bh, t2Bl, S, nullptr, S, nullptr, nullptr, SBh, SBl);             // S+=T@P
  G(t2Ah, t2Al, t2Bh, t2Bl, nullptr, nullptr, nullptr, P0Ah, P0Al, P0Bh, P0Bl);   // P2
  // X = F^2(t1)
  G(P0Ah, P0Al, t1Bh, t1Bl, nullptr, nullptr, nullptr, TAh, TAl, nullptr, nullptr);
  G(TAh, TAl, P0Bh, P0Bl, S, nullptr, X, nullptr, nullptr, XBh, XBl);
  // F^2 -> F^4   (P0 -> P1)
  G(P0Ah, P0Al, SBh, SBl, nullptr, nullptr, nullptr, TAh, TAl, nullptr, nullptr);
  G(TAh, TAl, P0Bh, P0Bl, S, nullptr, S, nullptr, nullptr, SBh, SBl);
  G(P0Ah, P0Al, P0Bh, P0Bl, nullptr, nullptr, nullptr, P1Ah, P1Al, P1Bh, P1Bl);
  // F^4 -> F^8   (P1 -> P0)
  G(P1Ah, P1Al, SBh, SBl, nullptr, nullptr, nullptr, TAh, TAl, nullptr, nullptr);
  G(TAh, TAl, P1Bh, P1Bl, S, nullptr, S, nullptr, nullptr, SBh, SBl);
  G(P1Ah, P1Al, P1Bh, P1Bl, nullptr, nullptr, nullptr, P0Ah, P0Al, P0Bh, P0Bl);
  // F^8 -> F^16  (P0 -> P1)
  G(P0Ah, P0Al, SBh, SBl, nullptr, nullptr, nullptr, TAh, TAl, nullptr, nullptr);
  G(TAh, TAl, P0Bh, P0Bl, S, nullptr, S, nullptr, nullptr, SBh, SBl);
  G(P0Ah, P0Al, P0Bh, P0Bl, nullptr, nullptr, nullptr, P1Ah, P1Al, P1Bh, P1Bl);
  // X = F^16(X) three times; last one fuses the final "+ t1"
  G(P1Ah, P1Al, XBh, XBl, nullptr, nullptr, nullptr, TAh, TAl, nullptr, nullptr);
  G(TAh, TAl, P1Bh, P1Bl, S, nullptr, X, nullptr, nullptr, XBh, XBl);
  G(P1Ah, P1Al, XBh, XBl, nullptr, nullptr, nullptr, TAh, TAl, nullptr, nullptr);
  G(TAh, TAl, P1Bh, P1Bl, S, nullptr, X, nullptr, nullptr, XBh, XBl);
  G(P1Ah, P1Al, XBh, XBl, nullptr, nullptr, nullptr, TAh, TAl, nullptr, nullptr);
  G(TAh, TAl, P1Bh, P1Bl, S, t1, X, nullptr, nullptr, nullptr, nullptr);
}

// Round 2
// 444.553 us; speedup vs baseline: 1.5074x; 1.5074x over previous
//
#include <hip/hip_runtime.h>

// ============================================================================
// t3 recurrence via affine-operator doubling + bf16x3 split MFMA GEMMs.
//
// Reference: t3=t1; repeat 50x { t3 = t1 + t2@t3; t3 = t1 + t3@t2 }; out=t3+t1
// Fused step: t3 <- C + t2 @ t3 @ t2,  C = t1 + t1@t2
// Operator F=(S,P): X -> S + P X P.  All P are powers of t2 (commute).
//   double:  S2k = Sk + Pk Sk Pk (2 mm), P2k = Pk Pk (1 mm)
//   compose: S(a+b) = Sa + Pa Sb Pa,  P(a+b) = Pa Pb
// Schedule: S1=C; double to F^16; X2=F^2(t1); compose F^32, F^48;
//           out = F^48(X2) + t1.   23 matmuls in 14 launches (9 full-GPU
//           via 2-job batching; grid.z selects job descriptor).
// ============================================================================

typedef __bf16 bf16;
typedef bf16 bf16x8 __attribute__((ext_vector_type(8)));
typedef float f32x4 __attribute__((ext_vector_type(4)));
typedef float f32x16 __attribute__((ext_vector_type(16)));

#define LD 1024
#define BM 128
#define BN 64
#define BK 64
#define NKS (LD / BK)   // 16 K-steps (halved barrier count vs BK=32)
#define SK 72           // LDS k-stride (bf16): 144B rows, 16B aligned, 4-way banks

struct Job {
  const bf16 *Ah, *Al, *Bh, *Bl;   // A row-major [m][k], B transposed [n][k]
  const float *C1, *C2;            // optional fp32 addends (output layout)
  float *Of;                       // optional fp32 output
  bf16 *Orh, *Orl;                 // optional bf16 hi/lo row-major (A-form)
  bf16 *Oth, *Otl;                 // optional bf16 hi/lo transposed (B-form)
};

__device__ __forceinline__ f32x16 mfma16(bf16x8 a, bf16x8 b, f32x16 c) {
  return __builtin_amdgcn_mfma_f32_32x32x16_bf16(a, b, c, 0, 0, 0);
}

__global__ __launch_bounds__(256) void gemm_k(Job j0, Job j1)
{
  __shared__ bf16 sA[2][2][BM * SK];   // [dbuf][hi/lo]  72 KiB
  __shared__ bf16 sB[2][2][BN * SK];   //                36 KiB

  const Job J = blockIdx.z ? j1 : j0;

  const int tid  = threadIdx.x;
  const int lane = tid & 63;
  const int wave = tid >> 6;

  // XCD-aware swizzle per 128-wg slice (128 % 8 == 0 -> bijective)
  const int id  = blockIdx.y * 16 + blockIdx.x;
  const int sid = (id & 7) * 16 + (id >> 3);
  const int bm = (sid >> 4) * BM;   // 0..7
  const int bn = (sid & 15) * BN;   // 0..15

  // staging: A-tile 128x64 (32 elem/thr per h/l), B-tile 64x64 (16 elem/thr)
  const int ar = tid >> 1;
  const int ac = (tid & 1) * 32;
  const int br = tid >> 2;
  const int bc = (tid & 3) * 16;

  const bf16* gAh = J.Ah + (size_t)(bm + ar) * LD + ac;
  const bf16* gAl = J.Al + (size_t)(bm + ar) * LD + ac;
  const bf16* gBh = J.Bh + (size_t)(bn + br) * LD + bc;
  const bf16* gBl = J.Bl + (size_t)(bn + br) * LD + bc;

  bf16x8 ra[2][4], rb[2][2];

  auto load_tile = [&](int kt) {
    const int o = kt * BK;
#pragma unroll
    for (int q = 0; q < 4; ++q) {
      ra[0][q] = *(const bf16x8*)(gAh + o + q * 8);
      ra[1][q] = *(const bf16x8*)(gAl + o + q * 8);
    }
#pragma unroll
    for (int q = 0; q < 2; ++q) {
      rb[0][q] = *(const bf16x8*)(gBh + o + q * 8);
      rb[1][q] = *(const bf16x8*)(gBl + o + q * 8);
    }
  };
  auto store_tile = [&](int buf) {
#pragma unroll
    for (int q = 0; q < 4; ++q) {
      *(bf16x8*)&sA[buf][0][ar * SK + ac + q * 8] = ra[0][q];
      *(bf16x8*)&sA[buf][1][ar * SK + ac + q * 8] = ra[1][q];
    }
#pragma unroll
    for (int q = 0; q < 2; ++q) {
      *(bf16x8*)&sB[buf][0][br * SK + bc + q * 8] = rb[0][q];
      *(bf16x8*)&sB[buf][1][br * SK + bc + q * 8] = rb[1][q];
    }
  };

  // wave -> 64x32 output: two 32x32 MFMA tiles stacked in m
  const int wm  = wave >> 1;
  const int wn  = wave & 1;
  const int l31 = lane & 31;
  const int lh  = lane >> 5;
  const int lh8 = lh * 8;

  const int aoff0 = (wm * 64 + l31) * SK + lh8;
  const int aoff1 = (wm * 64 + 32 + l31) * SK + lh8;
  const int boff  = (wn * 32 + l31) * SK + lh8;

  f32x16 acc0 = {0,0,0,0,0,0,0,0,0,0,0,0,0,0,0,0};
  f32x16 acc1 = {0,0,0,0,0,0,0,0,0,0,0,0,0,0,0,0};

  auto compute = [&](int buf) {
#pragma unroll
    for (int c = 0; c < 4; ++c) {          // four k=16 chunks
      const int co = c * 16;
      bf16x8 a0h = *(const bf16x8*)&sA[buf][0][aoff0 + co];
      bf16x8 a0l = *(const bf16x8*)&sA[buf][1][aoff0 + co];
      bf16x8 a1h = *(const bf16x8*)&sA[buf][0][aoff1 + co];
      bf16x8 a1l = *(const bf16x8*)&sA[buf][1][aoff1 + co];
      bf16x8 bh  = *(const bf16x8*)&sB[buf][0][boff + co];
      bf16x8 bl  = *(const bf16x8*)&sB[buf][1][boff + co];
      // bf16x3: hi*hi + hi*lo + lo*hi, two independent acc chains
      acc0 = mfma16(a0h, bh, acc0);
      acc1 = mfma16(a1h, bh, acc1);
      acc0 = mfma16(a0h, bl, acc0);
      acc1 = mfma16(a1h, bl, acc1);
      acc0 = mfma16(a0l, bh, acc0);
      acc1 = mfma16(a1l, bh, acc1);
    }
  };

  load_tile(0);
  store_tile(0);
  __syncthreads();
  int buf = 0;
  for (int kt = 0; kt < NKS; ++kt) {
    if (kt + 1 < NKS) load_tile(kt + 1);   // issue next-tile loads early
    compute(buf);
    if (kt + 1 < NKS) store_tile(buf ^ 1); // implicit vmcnt wait here
    __syncthreads();
    buf ^= 1;
  }
  // all waves past final barrier: LDS reusable as epilogue scratch

  const int gc = bn + wn * 32 + l31;
#pragma unroll
  for (int tf = 0; tf < 2; ++tf) {
    const int gr0 = bm + wm * 64 + tf * 32;
    float v[16];
#pragma unroll
    for (int r = 0; r < 16; ++r) v[r] = tf ? acc1[r] : acc0[r];

    // C/D layout (32x32x16): row = (r&3)+8*(r>>2)+4*lh, col = l31
    if (J.C1) {
#pragma unroll
      for (int r = 0; r < 16; ++r)
        v[r] += J.C1[(size_t)(gr0 + ((r & 3) + 8 * (r >> 2) + 4 * lh)) * LD + gc];
    }
    if (J.C2) {
#pragma unroll
      for (int r = 0; r < 16; ++r)
        v[r] += J.C2[(size_t)(gr0 + ((r & 3) + 8 * (r >> 2) + 4 * lh)) * LD + gc];
    }
    if (J.Of) {
#pragma unroll
      for (int r = 0; r < 16; ++r)
        J.Of[(size_t)(gr0 + ((r & 3) + 8 * (r >> 2) + 4 * lh)) * LD + gc] = v[r];
    }
    if (J.Orh) {
#pragma unroll
      for (int r = 0; r < 16; ++r) {
        float x = v[r];
        bf16 h  = (bf16)x;
        bf16 lo = (bf16)(x - (float)h);
        size_t idx = (size_t)(gr0 + ((r & 3) + 8 * (r >> 2) + 4 * lh)) * LD + gc;
        J.Orh[idx] = h;
        J.Orl[idx] = lo;
      }
    }
    if (J.Oth) {
      // per-wave private 32x33 f32 scratch in sA
      float* tl = ((float*)&sA[0][0][0]) + wave * (32 * 33);
#pragma unroll
      for (int r = 0; r < 16; ++r)
        tl[((r & 3) + 8 * (r >> 2) + 4 * lh) * 33 + l31] = v[r];
      float tv[16];
#pragma unroll
      for (int j = 0; j < 16; ++j)
        tv[j] = tl[(lh * 16 + j) * 33 + l31];      // lane owns col n=l31
      bf16x8 th0, th1, tb0, tb1;
#pragma unroll
      for (int j = 0; j < 16; ++j) {
        bf16 h  = (bf16)tv[j];
        bf16 lo = (bf16)(tv[j] - (float)h);
        if (j < 8) { th0[j] = h; tb0[j] = lo; }
        else       { th1[j - 8] = h; tb1[j - 8] = lo; }
      }
      bf16* ph = J.Oth + (size_t)gc * LD + gr0 + lh * 16;
      bf16* pl = J.Otl + (size_t)gc * LD + gr0 + lh * 16;
      *(bf16x8*)ph = th0; *(bf16x8*)(ph + 8) = th1;
      *(bf16x8*)pl = tb0; *(bf16x8*)(pl + 8) = tb1;
    }
  }
}

// One-time split/transpose of the fp32 inputs into A-form and B-form bf16.
__global__ __launch_bounds__(256) void prep_k(
    const float* __restrict__ t1, const float* __restrict__ t2,
    bf16* __restrict__ Ah1, bf16* __restrict__ Al1,
    bf16* __restrict__ Bh1, bf16* __restrict__ Bl1,
    bf16* __restrict__ Ah2, bf16* __restrict__ Al2,
    bf16* __restrict__ Bh2, bf16* __restrict__ Bl2)
{
  __shared__ float tl[64 * 65];
  const int z = blockIdx.z;
  const float* src = z ? t2 : t1;
  bf16* Ah = z ? Ah2 : Ah1;
  bf16* Al = z ? Al2 : Al1;
  bf16* Bh = z ? Bh2 : Bh1;
  bf16* Bl = z ? Bl2 : Bl1;

  const int tid = threadIdx.x;
  const int r0 = blockIdx.y * 64, c0 = blockIdx.x * 64;
  const int r  = tid >> 2;
  const int cc = (tid & 3) * 16;

  float vv[16];
#pragma unroll
  for (int q = 0; q < 4; ++q) {
    f32x4 x = *(const f32x4*)&src[(size_t)(r0 + r) * LD + c0 + cc + q * 4];
#pragma unroll
    for (int e = 0; e < 4; ++e) vv[q * 4 + e] = x[e];
  }
  bf16x8 h8[2], l8[2];
#pragma unroll
  for (int j = 0; j < 16; ++j) {
    bf16 h  = (bf16)vv[j];
    bf16 lo = (bf16)(vv[j] - (float)h);
    h8[j >> 3][j & 7] = h;
    l8[j >> 3][j & 7] = lo;
    tl[r * 65 + cc + j] = vv[j];
  }
  {
    bf16* p = Ah + (size_t)(r0 + r) * LD + c0 + cc;
    *(bf16x8*)p = h8[0]; *(bf16x8*)(p + 8) = h8[1];
    bf16* q = Al + (size_t)(r0 + r) * LD + c0 + cc;
    *(bf16x8*)q = l8[0]; *(bf16x8*)(q + 8) = l8[1];
  }
  __syncthreads();
  float tv[16];
#pragma unroll
  for (int j = 0; j < 16; ++j) tv[j] = tl[(cc + j) * 65 + r];
#pragma unroll
  for (int j = 0; j < 16; ++j) {
    bf16 h  = (bf16)tv[j];
    bf16 lo = (bf16)(tv[j] - (float)h);
    h8[j >> 3][j & 7] = h;
    l8[j >> 3][j & 7] = lo;
  }
  {
    bf16* p = Bh + (size_t)(c0 + r) * LD + r0 + cc;
    *(bf16x8*)p = h8[0]; *(bf16x8*)(p + 8) = h8[1];
    bf16* q = Bl + (size_t)(c0 + r) * LD + r0 + cc;
    *(bf16x8*)q = l8[0]; *(bf16x8*)(q + 8) = l8[1];
  }
}

extern "C" void kernel_launch(void* const* d_in, const int* in_sizes, int n_in,
                              void* d_out, int out_size, void* d_ws, size_t ws_size,
                              hipStream_t stream) {
  (void)in_sizes; (void)n_in; (void)out_size;
  const float* t1 = (const float*)d_in[0];
  const float* t2 = (const float*)d_in[1];
  float* X = (float*)d_out;

  const size_t F32B = (size_t)LD * LD * 4;   // 4 MB
  const size_t B16B = (size_t)LD * LD * 2;   // 2 MB
  if (ws_size < F32B + 22 * B16B) return;    // 48 MB scratch

  char* p = (char*)d_ws;
  float* S = (float*)p; p += F32B;
  // 11 bf16 hi/lo pairs (liveness-packed slots W0..W10)
  bf16 *Wh[11], *Wl[11];
  for (int i = 0; i < 11; ++i) {
    Wh[i] = (bf16*)p; p += B16B;
    Wl[i] = (bf16*)p; p += B16B;
  }
  // W0: t1A -> X2B      W1: t1B -> S2B/S8B -> P48B   W2: t2A   W3: t2B
  // W4: SB0 (S1/S4/S16) W5,W6: P2/P8/P32 A,B         W7,W8: P4/P16 A,B
  // W9: T (doubling) -> P48A                         W10: Tx/T2/T3

  auto job = [](const bf16* ah, const bf16* al, const bf16* bh, const bf16* bl,
                const float* c1, const float* c2, float* of,
                bf16* orh, bf16* orl, bf16* oth, bf16* otl) -> Job {
    return Job{ah, al, bh, bl, c1, c2, of, orh, orl, oth, otl};
  };
  auto L2j = [&](Job a, Job b) {
    gemm_k<<<dim3(16, 8, 2), 256, 0, stream>>>(a, b);
  };
  auto L1j = [&](Job a) {
    gemm_k<<<dim3(16, 8, 1), 256, 0, stream>>>(a, a);
  };

  prep_k<<<dim3(16, 16, 2), 256, 0, stream>>>(t1, t2,
      Wh[0], Wl[0], Wh[1], Wl[1], Wh[2], Wl[2], Wh[3], Wl[3]);

  // L1: S1 = t1 + t1@t2 -> S,SB0 | P2 = t2@t2 -> W5(A),W6(B)
  L2j(job(Wh[0],Wl[0], Wh[3],Wl[3], t1,nullptr, S, nullptr,nullptr, Wh[4],Wl[4]),
      job(Wh[2],Wl[2], Wh[3],Wl[3], nullptr,nullptr, nullptr, Wh[5],Wl[5], Wh[6],Wl[6]));
  // L2: T1 = t2@S1B -> W9 | Tx = P2@t1B -> W10
  L2j(job(Wh[2],Wl[2], Wh[4],Wl[4], nullptr,nullptr, nullptr, Wh[9],Wl[9], nullptr,nullptr),
      job(Wh[5],Wl[5], Wh[1],Wl[1], nullptr,nullptr, nullptr, Wh[10],Wl[10], nullptr,nullptr));
  // L3: S2 = S + T1@t2B -> S, S2B(W1)
  L1j(job(Wh[9],Wl[9], Wh[3],Wl[3], S,nullptr, S, nullptr,nullptr, Wh[1],Wl[1]));
  // L4: T = P2@S2B -> W9 | X2 = S2 + Tx@P2B -> X2B(W0)
  L2j(job(Wh[5],Wl[5], Wh[1],Wl[1], nullptr,nullptr, nullptr, Wh[9],Wl[9], nullptr,nullptr),
      job(Wh[10],Wl[10], Wh[6],Wl[6], S,nullptr, nullptr, nullptr,nullptr, Wh[0],Wl[0]));
  // L5: S4 = S + T@P2B -> S, SB0(W4) | P4 = P2@P2B -> W7(A),W8(B)
  L2j(job(Wh[9],Wl[9], Wh[6],Wl[6], S,nullptr, S, nullptr,nullptr, Wh[4],Wl[4]),
      job(Wh[5],Wl[5], Wh[6],Wl[6], nullptr,nullptr, nullptr, Wh[7],Wl[7], Wh[8],Wl[8]));
  // L6: T = P4@S4B -> W9
  L1j(job(Wh[7],Wl[7], Wh[4],Wl[4], nullptr,nullptr, nullptr, Wh[9],Wl[9], nullptr,nullptr));
  // L7: S8 = S + T@P4B -> S, S8B(W1) | P8 = P4@P4B -> W5(A),W6(B)
  L2j(job(Wh[9],Wl[9], Wh[8],Wl[8], S,nullptr, S, nullptr,nullptr, Wh[1],Wl[1]),
      job(Wh[7],Wl[7], Wh[8],Wl[8], nullptr,nullptr, nullptr, Wh[5],Wl[5], Wh[6],Wl[6]));
  // L8: T = P8@S8B -> W9
  L1j(job(Wh[5],Wl[5], Wh[1],Wl[1], nullptr,nullptr, nullptr, Wh[9],Wl[9], nullptr,nullptr));
  // L9: S16 = S + T@P8B -> S, SB0(W4) | P16 = P8@P8B -> W7(A),W8(B)
  L2j(job(Wh[9],Wl[9], Wh[6],Wl[6], S,nullptr, S, nullptr,nullptr, Wh[4],Wl[4]),
      job(Wh[5],Wl[5], Wh[6],Wl[6], nullptr,nullptr, nullptr, Wh[7],Wl[7], Wh[8],Wl[8]));
  // La: T = P16@S16B -> W9 | P32 = P16@P16B -> W5(A),W6(B)
  L2j(job(Wh[7],Wl[7], Wh[4],Wl[4], nullptr,nullptr, nullptr, Wh[9],Wl[9], nullptr,nullptr),
      job(Wh[7],Wl[7], Wh[8],Wl[8], nullptr,nullptr, nullptr, Wh[5],Wl[5], Wh[6],Wl[6]));
  // Lb: S32 = S + T@P16B -> S | T2 = P32@S16B -> W10
  L2j(job(Wh[9],Wl[9], Wh[8],Wl[8], S,nullptr, S, nullptr,nullptr, nullptr,nullptr),
      job(Wh[5],Wl[5], Wh[4],Wl[4], nullptr,nullptr, nullptr, Wh[10],Wl[10], nullptr,nullptr));
  // Lc: S48 = S + T2@P32B -> S | P48 = P16@P32B -> W9(A), W1(B)
  L2j(job(Wh[10],Wl[10], Wh[6],Wl[6], S,nullptr, S, nullptr,nullptr, nullptr,nullptr),
      job(Wh[7],Wl[7], Wh[6],Wl[6], nullptr,nullptr, nullptr, Wh[9],Wl[9], Wh[1],Wl[1]));
  // Ld: T3 = P48@X2B -> W10
  L1j(job(Wh[9],Wl[9], Wh[0],Wl[0], nullptr,nullptr, nullptr, Wh[10],Wl[10], nullptr,nullptr));
  // Le: out = S48 + t1 + T3@P48B -> d_out
  L1j(job(Wh[10],Wl[10], Wh[1],Wl[1], S,t1, X, nullptr,nullptr, nullptr,nullptr));
}